// Round 11
// baseline (615.759 us; speedup 1.0000x reference)
//
#include <hip/hip_runtime.h>

#define DIM 16
#define HID 256
#define NSTEPS 10
#define TILE_B 16    // 512 blocks = 2 blocks/CU = 32 waves/CU (100% occupancy cap)
#define NTHR 1024
#define LSH 264      // bf16 LDS row stride, multiple of 8 shorts (16 B) for aligned bf16x8 reads
                     // (R7: stride 268 -> misaligned ds_read_b128 -> 1.7x regression). Vector reads
                     // in this layout are <=2-way (free); the C-layout scalar writes 4-way conflict
                     // (16g mod 32) -- accepted: every fix tried (R7 pad, R9 XOR, R10 stagger) cost more.

typedef __attribute__((ext_vector_type(8))) short bf16x8;
typedef __attribute__((ext_vector_type(4))) float f32x4;

__device__ __forceinline__ unsigned short f2bf(float f) {
    unsigned u = __float_as_uint(f);
    u += 0x7fff + ((u >> 16) & 1);          // RNE
    return (unsigned short)(u >> 16);
}
__device__ __forceinline__ unsigned short f2bf_trunc(float f) {
    return (unsigned short)(__float_as_uint(f) >> 16);   // ds_write_b16_d16_hi path (0 VALU)
}
__device__ __forceinline__ float bf2f(unsigned short u) {
    return __uint_as_float((unsigned)u << 16);
}
__device__ __forceinline__ void silu_both(float x, float& h, float& d) {
    float s = __builtin_amdgcn_rcpf(1.0f + __expf(-x));   // v_rcp_f32: saves IEEE v_div_* sequence
    h = x * s;
    d = fmaf(h, 1.0f - s, s);               // silu' = s + h*(1-s)
}

// w2t[n][j] = bf16(W2[j][n]);  mt[n][j] = bf16(M[j][n]), M[j][n] = W2[j][n]*sum_i W1[i][j]*W3[n][i]
__global__ void cnf_setup(const float* __restrict__ W1, const float* __restrict__ W2,
                          const float* __restrict__ W3,
                          unsigned short* __restrict__ w2t, unsigned short* __restrict__ mt) {
    const int j = blockIdx.x;
    const int n = threadIdx.x;
    float g = 0.0f;
#pragma unroll
    for (int i = 0; i < DIM; ++i) g = fmaf(W1[i * HID + j], W3[n * DIM + i], g);
    const float w2 = W2[j * HID + n];
    w2t[n * HID + j] = f2bf(w2);
    mt [n * HID + j] = f2bf(w2 * g);
}

__global__ __launch_bounds__(NTHR, 8) void cnf_main(   // 8 waves/EU: forces VGPR<=64 so 2 blocks/CU
    const float* __restrict__ x,
    const float* __restrict__ W1, const float* __restrict__ b1,
    const float* __restrict__ b2, const float* __restrict__ b3,
    const unsigned short* __restrict__ w2t, const unsigned short* __restrict__ mt,
    const float* __restrict__ W3, float* __restrict__ out)
{
    __shared__ unsigned short zb[TILE_B][24];       // z bf16; 24-short rows: 12r mod 32 -> 2-way reads
    __shared__ unsigned short w1t[HID][24];         // W1^T bf16, same padding
    __shared__ unsigned short w3t[DIM][LSH];        // W3^T bf16 [n][k]
    __shared__ unsigned short h1s[TILE_B][LSH];     // h1
    __shared__ unsigned short d1s[TILE_B][LSH];     // d1
    __shared__ unsigned short h2s[TILE_B][LSH];     // h2 (separate buffer: no WAR barrier)
    __shared__ unsigned short d2s[TILE_B][LSH];     // d2
    __shared__ float fzp[8][TILE_B][DIM + 2];       // phase-3 k-slice partials (+2 pad: 2-way max)
    __shared__ float divp[8][TILE_B];               // per-v-wave divergence partials
    // total ~65.0 KB <= 80 KB -> 2 blocks/CU

    const int tid  = (int)threadIdx.x;
    const int lane = tid & 63;
    const int wv   = tid >> 6;            // 0..15
    const int g    = lane >> 4;           // quad 0..3
    const int r    = lane & 15;
    const int b0   = (int)blockIdx.x * TILE_B;
    const int row_u = tid >> 4, col_u = tid & 15;   // update mapping, valid for tid<256

    // ---- B-fragments for phase 2, loaded ONCE into registers (32 VGPRs/lane).
    // All uses fully unrolled -> compile-time indices -> stays in VGPRs (round-5 lesson).
    bf16x8 breg[8][2];
    const int n0w = (wv & 7) * 32;
    {
        const unsigned short* Bg = (wv < 8) ? w2t : mt;
#pragma unroll
        for (int k = 0; k < 8; ++k)
#pragma unroll
            for (int ct = 0; ct < 2; ++ct)
                breg[k][ct] = *(const bf16x8*)(Bg + (n0w + ct * 16 + r) * HID + k * 32 + g * 8);
    }

    // ---- per-thread bias/weight preloads (hoisted out of the stage loop) ----
    const int n_p1 = wv * 16 + r;                   // phase-1 column
    const float b1n = b1[n_p1];
    const float w1n = W1[DIM * HID + n_p1];         // t-row of W1
    const float b2r0 = b2[n0w + r], b2r1 = b2[n0w + 16 + r];
    float b3r = 0.0f;
    if (tid < 256) b3r = b3[col_u];

    // ---- one-time LDS builds ----
    if (tid < 512) {   // W1^T
        const int n = tid >> 1, kh = (tid & 1) * 8;
#pragma unroll
        for (int k = 0; k < 8; ++k) w1t[n][kh + k] = f2bf(W1[(kh + k) * HID + n]);
    }
    if (tid < 512) {   // W3^T
        const int n = tid >> 5, k0 = (tid & 31) * 8;
#pragma unroll
        for (int j = 0; j < 8; ++j) w3t[n][k0 + j] = f2bf(W3[(k0 + j) * DIM + n]);
    }
    // ---- z state: one element per thread (tid<256), fp32 in registers ----
    float zbase = 0.0f, zacc = 0.0f, lacc = 0.0f, logp = 0.0f;
    if (tid < 256) {
        zbase = x[(b0 + row_u) * DIM + col_u];
        zb[row_u][col_u] = f2bf(zbase);
    }

    const float dt = 0.1f, dt6 = dt / 6.0f;

    for (int it = 0; it < NSTEPS * 4; ++it) {
        const int s = it & 3;
        const int step = it >> 2;
        const float t0 = dt * (float)step;
        const float tcur = t0 + ((s == 0) ? 0.0f : (s == 3) ? dt : 0.5f * dt);
        const float wst = (s == 1 || s == 2) ? 2.0f : 1.0f;
        __syncthreads();   // B1: zb ready; h1s/d1s/fzp/divp free

        // ---------- phase 1 (MFMA): pre1 = [z,t]@W1+b1 -> h1,d1 bf16 (wave wv owns n-tile wv) ----------
        {
            const bf16x8 zf = {0, 0, 0, 0, 0, 0, 0, 0};
            bf16x8 az = (g < 2) ? *(const bf16x8*)&zb[r][g * 8] : zf;
            bf16x8 bw = (g < 2) ? *(const bf16x8*)&w1t[n_p1][g * 8] : zf;
            const float bb = fmaf(tcur, w1n, b1n);   // t-row folded into bias
            f32x4 c = {0.f, 0.f, 0.f, 0.f};
            c = __builtin_amdgcn_mfma_f32_16x16x32_bf16(az, bw, c, 0, 0, 0);
#pragma unroll
            for (int q = 0; q < 4; ++q) {
                float h, d;
                silu_both(c[q] + bb, h, d);
                h1s[g * 4 + q][n_p1] = f2bf_trunc(h);
                d1s[g * 4 + q][n_p1] = f2bf_trunc(d);
            }
        }
        __syncthreads();   // B2: h1/d1 ready

        // ---------- phase 2 (MFMA, operand-split, B from registers; FULLY unrolled) ----------
        // waves 0-7: h1@W2 (their breg = W2^T slices); waves 8-15: d1@M (breg = M^T slices)
        f32x4 cc[2];
        {
            const unsigned short (*aT)[LSH] = (wv < 8) ? h1s : d1s;
            cc[0] = (f32x4){0.f, 0.f, 0.f, 0.f};
            cc[1] = (f32x4){0.f, 0.f, 0.f, 0.f};
#pragma unroll
            for (int k = 0; k < 8; ++k) {
                bf16x8 af = *(const bf16x8*)&aT[r][k * 32 + g * 8];
#pragma unroll
                for (int ct = 0; ct < 2; ++ct)
                    cc[ct] = __builtin_amdgcn_mfma_f32_16x16x32_bf16(af, breg[k][ct], cc[ct], 0, 0, 0);
            }
        }
        // no barrier: h2/d2 go to separate buffers
        if (wv < 8) {   // h2-waves: silu epilogue -> h2s/d2s
#pragma unroll
            for (int ct = 0; ct < 2; ++ct) {
                const int n = n0w + ct * 16 + r;
                const float bb = (ct == 0) ? b2r0 : b2r1;
#pragma unroll
                for (int q = 0; q < 4; ++q) {
                    float h, d;
                    silu_both(cc[ct][q] + bb, h, d);
                    h2s[g * 4 + q][n] = f2bf_trunc(h);
                    d2s[g * 4 + q][n] = f2bf_trunc(d);
                }
            }
        }
        __syncthreads();   // B4: h2/d2 ready

        if (wv < 8) {
            // ---------- phase 3 (MFMA, h2-waves): fz = h2@W3, wave wv owns k-slice wv*32 ----------
            bf16x8 a = *(const bf16x8*)&h2s[r][wv * 32 + g * 8];
            bf16x8 b = *(const bf16x8*)&w3t[r][wv * 32 + g * 8];
            f32x4 c3 = {0.f, 0.f, 0.f, 0.f};
            c3 = __builtin_amdgcn_mfma_f32_16x16x32_bf16(a, b, c3, 0, 0, 0);
#pragma unroll
            for (int q = 0; q < 4; ++q) fzp[wv][g * 4 + q][r] = c3[q];
        } else {
            // ---------- v-waves: div partial = sum_n d2 .* v  (cc holds v = d1@M) ----------
            float p[4] = {0.f, 0.f, 0.f, 0.f};
#pragma unroll
            for (int ct = 0; ct < 2; ++ct) {
                const int n = n0w + ct * 16 + r;
#pragma unroll
                for (int q = 0; q < 4; ++q) {
                    const float d2v = bf2f(d2s[g * 4 + q][n]);
                    p[q] = fmaf(d2v, cc[ct][q], p[q]);
                }
            }
#pragma unroll
            for (int m = 1; m < 16; m <<= 1)
#pragma unroll
                for (int q = 0; q < 4; ++q) p[q] += __shfl_xor(p[q], m, 64);
            if (r == 0)
#pragma unroll
                for (int q = 0; q < 4; ++q) divp[wv - 8][g * 4 + q] = p[q];
        }
        __syncthreads();   // B5: fzp, divp ready

        // ---------- RK4 stage update (fp32, registers; tid<256) ----------
        if (tid < 256) {
            float fz = b3r;
#pragma unroll
            for (int ks = 0; ks < 8; ++ks) fz += fzp[ks][row_u][col_u];
            zacc = fmaf(wst, fz, zacc);
            float znext;
            if (s < 3) {
                const float coef = (s == 2) ? dt : 0.5f * dt;
                znext = fmaf(coef, fz, zbase);
            } else {
                zbase = fmaf(dt6, zacc, zbase);
                znext = zbase;
                zacc = 0.0f;
            }
            zb[row_u][col_u] = f2bf(znext);
            if (col_u == 0) {
                float dv = 0.0f;
#pragma unroll
                for (int w = 0; w < 8; ++w) dv += divp[w][row_u];
                lacc = fmaf(-wst, dv, lacc);
                if (s == 3) { logp = fmaf(dt6, lacc, logp); lacc = 0.0f; }
            }
        }
    }

    // ---------- epilogue: logpz - logp1 ----------
    __syncthreads();
    if (tid < 256) {
        float ss = zbase * zbase;
#pragma unroll
        for (int m = 1; m < 16; m <<= 1) ss += __shfl_xor(ss, m, 64);
        if (col_u == 0)
            out[b0 + row_u] = -0.5f * (ss + (float)DIM * 1.8378770664093453f) - logp;
    }
}

extern "C" void kernel_launch(void* const* d_in, const int* in_sizes, int n_in,
                              void* d_out, int out_size, void* d_ws, size_t ws_size,
                              hipStream_t stream) {
    (void)in_sizes; (void)n_in; (void)out_size; (void)ws_size;
    const float* x  = (const float*)d_in[0];
    const float* W1 = (const float*)d_in[1];
    const float* b1 = (const float*)d_in[2];
    const float* W2 = (const float*)d_in[3];
    const float* b2 = (const float*)d_in[4];
    const float* W3 = (const float*)d_in[5];
    const float* b3 = (const float*)d_in[6];
    unsigned short* w2t = (unsigned short*)d_ws;               // 128 KB
    unsigned short* mt  = w2t + HID * HID;                     // 128 KB

    cnf_setup<<<HID, HID, 0, stream>>>(W1, W2, W3, w2t, mt);
    cnf_main<<<8192 / TILE_B, NTHR, 0, stream>>>(x, W1, b1, b2, b3, w2t, mt, W3, (float*)d_out);
}

// Round 12
// 229.501 us; speedup vs baseline: 2.6830x; 2.6830x over previous
//
#include <hip/hip_runtime.h>

#define DIM 16
#define HID 256
#define NSTEPS 10
#define TILE_B 32
#define NTHR 1024
#define LSH 264      // bf16 LDS row stride, multiple of 8 shorts (16 B) for aligned bf16x8 reads
                     // (R7: stride 268 -> misaligned ds_read_b128 -> 1.7x regression). Vector reads
                     // in this layout are conflict-free; the C-layout scalar writes 4-way conflict
                     // (16g mod 32) is ACCEPTED: R7 pad, R9 XOR-swizzle, R10 temporal stagger all
                     // cost more than the ~10% the conflicts cost. R11: 2 blocks/CU infeasible --
                     // 32 waves x 16KB breg = 512 KB = entire CU register file -> spills.

typedef __attribute__((ext_vector_type(8))) short bf16x8;
typedef __attribute__((ext_vector_type(4))) float f32x4;

__device__ __forceinline__ unsigned short f2bf(float f) {
    unsigned u = __float_as_uint(f);
    u += 0x7fff + ((u >> 16) & 1);          // RNE
    return (unsigned short)(u >> 16);
}
__device__ __forceinline__ unsigned short f2bf_trunc(float f) {
    return (unsigned short)(__float_as_uint(f) >> 16);   // ds_write_b16_d16_hi path (0 VALU)
}
__device__ __forceinline__ float bf2f(unsigned short u) {
    return __uint_as_float((unsigned)u << 16);
}
__device__ __forceinline__ void silu_both(float x, float& h, float& d) {
    float s = __builtin_amdgcn_rcpf(1.0f + __expf(-x));   // v_rcp_f32: saves IEEE v_div_* (R9: -16% VALU)
    h = x * s;
    d = fmaf(h, 1.0f - s, s);               // silu' = s + h*(1-s)
}

// w2t[n][j] = bf16(W2[j][n]);  mt[n][j] = bf16(M[j][n]), M[j][n] = W2[j][n]*sum_i W1[i][j]*W3[n][i]
__global__ void cnf_setup(const float* __restrict__ W1, const float* __restrict__ W2,
                          const float* __restrict__ W3,
                          unsigned short* __restrict__ w2t, unsigned short* __restrict__ mt) {
    const int j = blockIdx.x;
    const int n = threadIdx.x;
    float g = 0.0f;
#pragma unroll
    for (int i = 0; i < DIM; ++i) g = fmaf(W1[i * HID + j], W3[n * DIM + i], g);
    const float w2 = W2[j * HID + n];
    w2t[n * HID + j] = f2bf(w2);
    mt [n * HID + j] = f2bf(w2 * g);
}

__global__ __launch_bounds__(NTHR, 4) void cnf_main(
    const float* __restrict__ x,
    const float* __restrict__ W1, const float* __restrict__ b1,
    const float* __restrict__ b2, const float* __restrict__ b3,
    const unsigned short* __restrict__ w2t, const unsigned short* __restrict__ mt,
    const float* __restrict__ W3, float* __restrict__ out)
{
    __shared__ unsigned short zb[TILE_B][24];       // z bf16; 24-short rows (12 dw): phase-1 b128
                                                    // reads 2-way max (16-short rows were 4-way)
    __shared__ unsigned short w1t[HID][24];         // W1^T bf16, same padding (cols 16-23 unused)
    __shared__ unsigned short w3t[DIM][LSH];        // W3^T bf16 [n][k]
    __shared__ unsigned short h1s[TILE_B][LSH];     // h1
    __shared__ unsigned short d1s[TILE_B][LSH];     // d1
    __shared__ unsigned short h2s[TILE_B][LSH];     // h2 (separate buffer: no WAR barrier)
    __shared__ unsigned short d2s[TILE_B][LSH];     // d2
    __shared__ float fzp[8][TILE_B][DIM + 2];       // phase-3 k-slice partials (+2 pad: 2-way max)
    __shared__ float divp[8][TILE_B];               // per-v-wave divergence partials

    const int tid  = (int)threadIdx.x;
    const int lane = tid & 63;
    const int wv   = tid >> 6;            // 0..15
    const int g    = lane >> 4;           // quad 0..3
    const int r    = lane & 15;
    const int b0   = (int)blockIdx.x * TILE_B;
    const int row_u = tid >> 4, col_u = tid & 15;   // update mapping, valid for tid<512

    // ---- B-fragments for phase 2, loaded ONCE into registers (64 VGPRs/lane).
    // All uses fully unrolled -> compile-time indices -> stays in VGPRs (round-5 lesson).
    bf16x8 breg[8][2];
    const int n0w = (wv & 7) * 32;
    {
        const unsigned short* Bg = (wv < 8) ? w2t : mt;
#pragma unroll
        for (int k = 0; k < 8; ++k)
#pragma unroll
            for (int ct = 0; ct < 2; ++ct)
                breg[k][ct] = *(const bf16x8*)(Bg + (n0w + ct * 16 + r) * HID + k * 32 + g * 8);
    }

    // ---- per-thread bias/weight preloads (hoisted out of the stage loop) ----
    const int n_p1 = wv * 16 + r;                   // phase-1 column
    const float b1n = b1[n_p1];
    const float w1n = W1[DIM * HID + n_p1];         // t-row of W1
    const float b2r0 = b2[n0w + r], b2r1 = b2[n0w + 16 + r];
    float b3r = 0.0f;
    if (tid < 512) b3r = b3[col_u];

    // ---- one-time LDS builds ----
    if (tid < 512) {   // W1^T
        const int n = tid >> 1, kh = (tid & 1) * 8;
#pragma unroll
        for (int k = 0; k < 8; ++k) w1t[n][kh + k] = f2bf(W1[(kh + k) * HID + n]);
    }
    if (tid < 512) {   // W3^T
        const int n = tid >> 5, k0 = (tid & 31) * 8;
#pragma unroll
        for (int j = 0; j < 8; ++j) w3t[n][k0 + j] = f2bf(W3[(k0 + j) * DIM + n]);
    }
    // ---- z state: one element per thread (tid<512), fp32 in registers ----
    float zbase = 0.0f, zacc = 0.0f, lacc = 0.0f, logp = 0.0f;
    if (tid < 512) {
        zbase = x[(b0 + row_u) * DIM + col_u];
        zb[row_u][col_u] = f2bf(zbase);
    }

    const float dt = 0.1f, dt6 = dt / 6.0f;

    for (int it = 0; it < NSTEPS * 4; ++it) {
        const int s = it & 3;
        const int step = it >> 2;
        const float t0 = dt * (float)step;
        const float tcur = t0 + ((s == 0) ? 0.0f : (s == 3) ? dt : 0.5f * dt);
        const float wst = (s == 1 || s == 2) ? 2.0f : 1.0f;
        __syncthreads();   // B1: zb ready; h1s/d1s/fzp/divp free

        // ---------- phase 1 (MFMA): pre1 = [z,t]@W1+b1 -> h1,d1 bf16 (wave wv owns n-tile wv) ----------
        {
            const bf16x8 zf = {0, 0, 0, 0, 0, 0, 0, 0};
            bf16x8 az[2], bw;
#pragma unroll
            for (int rt = 0; rt < 2; ++rt)
                az[rt] = (g < 2) ? *(const bf16x8*)&zb[rt * 16 + r][g * 8] : zf;
            bw = (g < 2) ? *(const bf16x8*)&w1t[n_p1][g * 8] : zf;
            const float bb = fmaf(tcur, w1n, b1n);   // t-row folded into bias
#pragma unroll
            for (int rt = 0; rt < 2; ++rt) {
                f32x4 c = {0.f, 0.f, 0.f, 0.f};
                c = __builtin_amdgcn_mfma_f32_16x16x32_bf16(az[rt], bw, c, 0, 0, 0);
#pragma unroll
                for (int q = 0; q < 4; ++q) {
                    float h, d;
                    silu_both(c[q] + bb, h, d);
                    h1s[rt * 16 + g * 4 + q][n_p1] = f2bf_trunc(h);
                    d1s[rt * 16 + g * 4 + q][n_p1] = f2bf_trunc(d);
                }
            }
        }
        __syncthreads();   // B2: h1/d1 ready

        // ---------- phase 2 (MFMA, operand-split, B from registers; FULLY unrolled) ----------
        f32x4 cc[2][2];
        {
            const unsigned short (*aT)[LSH] = (wv < 8) ? h1s : d1s;
#pragma unroll
            for (int a = 0; a < 2; ++a)
#pragma unroll
                for (int b = 0; b < 2; ++b) cc[a][b] = (f32x4){0.f, 0.f, 0.f, 0.f};
#pragma unroll
            for (int k = 0; k < 8; ++k) {
                bf16x8 af[2];
#pragma unroll
                for (int rt = 0; rt < 2; ++rt)
                    af[rt] = *(const bf16x8*)&aT[rt * 16 + r][k * 32 + g * 8];
#pragma unroll
                for (int rt = 0; rt < 2; ++rt)
#pragma unroll
                    for (int ct = 0; ct < 2; ++ct)
                        cc[rt][ct] = __builtin_amdgcn_mfma_f32_16x16x32_bf16(af[rt], breg[k][ct], cc[rt][ct], 0, 0, 0);
            }
        }
        // no barrier: h2/d2 go to separate buffers
        if (wv < 8) {   // h2-waves: silu epilogue -> h2s/d2s
#pragma unroll
            for (int ct = 0; ct < 2; ++ct) {
                const int n = n0w + ct * 16 + r;
                const float bb = (ct == 0) ? b2r0 : b2r1;
#pragma unroll
                for (int rt = 0; rt < 2; ++rt)
#pragma unroll
                    for (int q = 0; q < 4; ++q) {
                        float h, d;
                        silu_both(cc[rt][ct][q] + bb, h, d);
                        h2s[rt * 16 + g * 4 + q][n] = f2bf_trunc(h);
                        d2s[rt * 16 + g * 4 + q][n] = f2bf_trunc(d);
                    }
            }
        }
        __syncthreads();   // B4: h2/d2 ready

        // ---------- phase 3 (MFMA): fz = h2@W3, k split 8 ways x 2 b-tiles across 16 waves ----------
        {
            const int rt3 = wv & 1, q3 = wv >> 1;
            bf16x8 a = *(const bf16x8*)&h2s[rt3 * 16 + r][q3 * 32 + g * 8];
            bf16x8 b = *(const bf16x8*)&w3t[r][q3 * 32 + g * 8];
            f32x4 c3 = {0.f, 0.f, 0.f, 0.f};
            c3 = __builtin_amdgcn_mfma_f32_16x16x32_bf16(a, b, c3, 0, 0, 0);
#pragma unroll
            for (int q = 0; q < 4; ++q) fzp[q3][rt3 * 16 + g * 4 + q][r] = c3[q];
        }
        if (wv >= 8) {   // v-waves: div partial = sum_n d2 .* v  (cc holds v = d1@M)
            float p[2][4];
#pragma unroll
            for (int rt = 0; rt < 2; ++rt)
#pragma unroll
                for (int q = 0; q < 4; ++q) p[rt][q] = 0.0f;
#pragma unroll
            for (int ct = 0; ct < 2; ++ct) {
                const int n = n0w + ct * 16 + r;
#pragma unroll
                for (int rt = 0; rt < 2; ++rt)
#pragma unroll
                    for (int q = 0; q < 4; ++q) {
                        const float d2v = bf2f(d2s[rt * 16 + g * 4 + q][n]);
                        p[rt][q] = fmaf(d2v, cc[rt][ct][q], p[rt][q]);
                    }
            }
#pragma unroll
            for (int m = 1; m < 16; m <<= 1)
#pragma unroll
                for (int rt = 0; rt < 2; ++rt)
#pragma unroll
                    for (int q = 0; q < 4; ++q) p[rt][q] += __shfl_xor(p[rt][q], m, 64);
            if (r == 0)
#pragma unroll
                for (int rt = 0; rt < 2; ++rt)
#pragma unroll
                    for (int q = 0; q < 4; ++q) divp[wv - 8][rt * 16 + g * 4 + q] = p[rt][q];
        }
        __syncthreads();   // B5: fzp, divp ready

        // ---------- RK4 stage update (fp32, registers; tid<512) ----------
        if (tid < 512) {
            float fz = b3r;
#pragma unroll
            for (int ks = 0; ks < 8; ++ks) fz += fzp[ks][row_u][col_u];
            zacc = fmaf(wst, fz, zacc);
            float znext;
            if (s < 3) {
                const float coef = (s == 2) ? dt : 0.5f * dt;
                znext = fmaf(coef, fz, zbase);
            } else {
                zbase = fmaf(dt6, zacc, zbase);
                znext = zbase;
                zacc = 0.0f;
            }
            zb[row_u][col_u] = f2bf(znext);
            if (col_u == 0) {
                float dv = 0.0f;
#pragma unroll
                for (int w = 0; w < 8; ++w) dv += divp[w][row_u];
                lacc = fmaf(-wst, dv, lacc);
                if (s == 3) { logp = fmaf(dt6, lacc, logp); lacc = 0.0f; }
            }
        }
    }

    // ---------- epilogue: logpz - logp1 ----------
    __syncthreads();
    if (tid < 512) {
        float ss = zbase * zbase;
#pragma unroll
        for (int m = 1; m < 16; m <<= 1) ss += __shfl_xor(ss, m, 64);
        if (col_u == 0)
            out[b0 + row_u] = -0.5f * (ss + (float)DIM * 1.8378770664093453f) - logp;
    }
}

extern "C" void kernel_launch(void* const* d_in, const int* in_sizes, int n_in,
                              void* d_out, int out_size, void* d_ws, size_t ws_size,
                              hipStream_t stream) {
    (void)in_sizes; (void)n_in; (void)out_size; (void)ws_size;
    const float* x  = (const float*)d_in[0];
    const float* W1 = (const float*)d_in[1];
    const float* b1 = (const float*)d_in[2];
    const float* W2 = (const float*)d_in[3];
    const float* b2 = (const float*)d_in[4];
    const float* W3 = (const float*)d_in[5];
    const float* b3 = (const float*)d_in[6];
    unsigned short* w2t = (unsigned short*)d_ws;               // 128 KB
    unsigned short* mt  = w2t + HID * HID;                     // 128 KB

    cnf_setup<<<HID, HID, 0, stream>>>(W1, W2, W3, w2t, mt);
    cnf_main<<<8192 / TILE_B, NTHR, 0, stream>>>(x, W1, b1, b2, b3, w2t, mt, W3, (float*)d_out);
}

// Round 13
// 225.391 us; speedup vs baseline: 2.7320x; 1.0182x over previous
//
#include <hip/hip_runtime.h>

#define DIM 16
#define HID 256
#define NSTEPS 10
#define TILE_B 32
#define NTHR 1024
#define LSH 264      // bf16 LDS row stride, multiple of 8 shorts (16 B) for aligned bf16x8 reads
                     // (R7: stride 268 -> misaligned ds_read_b128 -> 1.7x regression).
                     // Bank fix (R13): col' = col ^ (16*((row>>3)&1)) -- 16-short granule keeps
                     // alignment; flips only bank bit 3. Writes (row bit3 = [g>=2]): 4 g-windows
                     // -> 32 distinct banks (free). Reads (row bit3 = [r>=8]): stays exactly 2-way
                     // (free). Unlike R9's (row&12)<<2 whose bit-5 flipped bank bit 4 into the
                     // read sweep. Both XORs are per-lane constants: zero extra VALU.

typedef __attribute__((ext_vector_type(8))) short bf16x8;
typedef __attribute__((ext_vector_type(4))) float f32x4;

__device__ __forceinline__ unsigned short f2bf(float f) {
    unsigned u = __float_as_uint(f);
    u += 0x7fff + ((u >> 16) & 1);          // RNE
    return (unsigned short)(u >> 16);
}
__device__ __forceinline__ unsigned short f2bf_trunc(float f) {
    return (unsigned short)(__float_as_uint(f) >> 16);   // ds_write_b16_d16_hi path (0 VALU)
}
__device__ __forceinline__ float bf2f(unsigned short u) {
    return __uint_as_float((unsigned)u << 16);
}
__device__ __forceinline__ void silu_both(float x, float& h, float& d) {
    float s = __builtin_amdgcn_rcpf(1.0f + __expf(-x));   // v_rcp_f32: saves IEEE v_div_* (R9: -16% VALU)
    h = x * s;
    d = fmaf(h, 1.0f - s, s);               // silu' = s + h*(1-s)
}

// w2t[n][j] = bf16(W2[j][n]);  mt[n][j] = bf16(M[j][n]), M[j][n] = W2[j][n]*sum_i W1[i][j]*W3[n][i]
__global__ void cnf_setup(const float* __restrict__ W1, const float* __restrict__ W2,
                          const float* __restrict__ W3,
                          unsigned short* __restrict__ w2t, unsigned short* __restrict__ mt) {
    const int j = blockIdx.x;
    const int n = threadIdx.x;
    float g = 0.0f;
#pragma unroll
    for (int i = 0; i < DIM; ++i) g = fmaf(W1[i * HID + j], W3[n * DIM + i], g);
    const float w2 = W2[j * HID + n];
    w2t[n * HID + j] = f2bf(w2);
    mt [n * HID + j] = f2bf(w2 * g);
}

__global__ __launch_bounds__(NTHR, 4) void cnf_main(
    const float* __restrict__ x,
    const float* __restrict__ W1, const float* __restrict__ b1,
    const float* __restrict__ b2, const float* __restrict__ b3,
    const unsigned short* __restrict__ w2t, const unsigned short* __restrict__ mt,
    const float* __restrict__ W3, float* __restrict__ out)
{
    __shared__ unsigned short zb[TILE_B][24];       // z bf16; 24-short rows: 2-way reads (free)
    __shared__ unsigned short w1t[HID][24];         // W1^T bf16, same padding (cols 16-23 unused)
    __shared__ unsigned short w3t[DIM][LSH];        // W3^T bf16 [n][k] (unswizzled: 2-way reads)
    __shared__ unsigned short h1s[TILE_B][LSH];     // h1  (col-swizzled)
    __shared__ unsigned short d1s[TILE_B][LSH];     // d1  (swizzled)
    __shared__ unsigned short h2s[TILE_B][LSH];     // h2  (swizzled; separate buffer: no WAR barrier)
    __shared__ unsigned short d2s[TILE_B][LSH];     // d2  (swizzled)
    __shared__ float fzp[4][TILE_B][DIM + 2];       // phase-3 k-slice partials (4 spans of 64)
    __shared__ float divp[8][TILE_B];               // per-v-wave divergence partials

    const int tid  = (int)threadIdx.x;
    const int lane = tid & 63;
    const int wv   = tid >> 6;            // 0..15
    const int g    = lane >> 4;           // quad 0..3
    const int r    = lane & 15;
    const int b0   = (int)blockIdx.x * TILE_B;
    const int row_u = tid >> 4, col_u = tid & 15;   // update mapping, valid for tid<512
    const int wx   = (g >> 1) << 4;       // write-side swizzle: rows g*4+q have bit3=[g>=2]
    const int goff = (g * 8) ^ (((r >> 3) & 1) << 4);   // read-side: rows rt*16+r, bit3=[r>=8]

    // ---- B-fragments for phase 2, loaded ONCE into registers (64 VGPRs/lane).
    // All uses fully unrolled -> compile-time indices -> stays in VGPRs (round-5 lesson).
    bf16x8 breg[8][2];
    const int n0w = (wv & 7) * 32;
    {
        const unsigned short* Bg = (wv < 8) ? w2t : mt;
#pragma unroll
        for (int k = 0; k < 8; ++k)
#pragma unroll
            for (int ct = 0; ct < 2; ++ct)
                breg[k][ct] = *(const bf16x8*)(Bg + (n0w + ct * 16 + r) * HID + k * 32 + g * 8);
    }

    // ---- per-thread bias/weight preloads (hoisted out of the stage loop) ----
    const int n_p1 = wv * 16 + r;                   // phase-1 column
    const int nw_p1 = n_p1 ^ wx;                    // swizzled write column
    const float b1n = b1[n_p1];
    const float w1n = W1[DIM * HID + n_p1];         // t-row of W1
    const float b2r0 = b2[n0w + r], b2r1 = b2[n0w + 16 + r];
    float b3r = 0.0f;
    if (tid < 512) b3r = b3[col_u];

    // ---- one-time LDS builds ----
    if (tid < 512) {   // W1^T
        const int n = tid >> 1, kh = (tid & 1) * 8;
#pragma unroll
        for (int k = 0; k < 8; ++k) w1t[n][kh + k] = f2bf(W1[(kh + k) * HID + n]);
    }
    if (tid < 512) {   // W3^T
        const int n = tid >> 5, k0 = (tid & 31) * 8;
#pragma unroll
        for (int j = 0; j < 8; ++j) w3t[n][k0 + j] = f2bf(W3[(k0 + j) * DIM + n]);
    }
    // ---- z state: one element per thread (tid<512), fp32 in registers ----
    float zbase = 0.0f, zacc = 0.0f, lacc = 0.0f, logp = 0.0f;
    if (tid < 512) {
        zbase = x[(b0 + row_u) * DIM + col_u];
        zb[row_u][col_u] = f2bf(zbase);
    }

    const float dt = 0.1f, dt6 = dt / 6.0f;

    for (int it = 0; it < NSTEPS * 4; ++it) {
        const int s = it & 3;
        const int step = it >> 2;
        const float t0 = dt * (float)step;
        const float tcur = t0 + ((s == 0) ? 0.0f : (s == 3) ? dt : 0.5f * dt);
        const float wst = (s == 1 || s == 2) ? 2.0f : 1.0f;
        __syncthreads();   // B1: zb ready; h1s/d1s/fzp/divp free

        // ---------- phase 1 (MFMA): pre1 = [z,t]@W1+b1 -> h1,d1 bf16 (wave wv owns n-tile wv) ----------
        {
            const bf16x8 zf = {0, 0, 0, 0, 0, 0, 0, 0};
            bf16x8 az[2], bw;
#pragma unroll
            for (int rt = 0; rt < 2; ++rt)
                az[rt] = (g < 2) ? *(const bf16x8*)&zb[rt * 16 + r][g * 8] : zf;
            bw = (g < 2) ? *(const bf16x8*)&w1t[n_p1][g * 8] : zf;
            const float bb = fmaf(tcur, w1n, b1n);   // t-row folded into bias
#pragma unroll
            for (int rt = 0; rt < 2; ++rt) {
                f32x4 c = {0.f, 0.f, 0.f, 0.f};
                c = __builtin_amdgcn_mfma_f32_16x16x32_bf16(az[rt], bw, c, 0, 0, 0);
#pragma unroll
                for (int q = 0; q < 4; ++q) {
                    float h, d;
                    silu_both(c[q] + bb, h, d);
                    h1s[rt * 16 + g * 4 + q][nw_p1] = f2bf_trunc(h);
                    d1s[rt * 16 + g * 4 + q][nw_p1] = f2bf_trunc(d);
                }
            }
        }
        __syncthreads();   // B2: h1/d1 ready

        // ---------- phase 2 (MFMA, operand-split, B from registers; FULLY unrolled) ----------
        f32x4 cc[2][2];
        {
            const unsigned short (*aT)[LSH] = (wv < 8) ? h1s : d1s;
#pragma unroll
            for (int a = 0; a < 2; ++a)
#pragma unroll
                for (int b = 0; b < 2; ++b) cc[a][b] = (f32x4){0.f, 0.f, 0.f, 0.f};
#pragma unroll
            for (int k = 0; k < 8; ++k) {
                bf16x8 af[2];
#pragma unroll
                for (int rt = 0; rt < 2; ++rt)
                    af[rt] = *(const bf16x8*)&aT[rt * 16 + r][k * 32 + goff];
#pragma unroll
                for (int rt = 0; rt < 2; ++rt)
#pragma unroll
                    for (int ct = 0; ct < 2; ++ct)
                        cc[rt][ct] = __builtin_amdgcn_mfma_f32_16x16x32_bf16(af[rt], breg[k][ct], cc[rt][ct], 0, 0, 0);
            }
        }
        // no barrier: h2/d2 go to separate buffers
        if (wv < 8) {   // h2-waves: silu epilogue -> h2s/d2s (swizzled cols)
#pragma unroll
            for (int ct = 0; ct < 2; ++ct) {
                const int nw = (n0w + ct * 16 + r) ^ wx;
                const float bb = (ct == 0) ? b2r0 : b2r1;
#pragma unroll
                for (int rt = 0; rt < 2; ++rt)
#pragma unroll
                    for (int q = 0; q < 4; ++q) {
                        float h, d;
                        silu_both(cc[rt][ct][q] + bb, h, d);
                        h2s[rt * 16 + g * 4 + q][nw] = f2bf_trunc(h);
                        d2s[rt * 16 + g * 4 + q][nw] = f2bf_trunc(d);
                    }
            }
        }
        __syncthreads();   // B4: h2/d2 ready

        if (wv < 8) {
            // ---------- phase 3 (MFMA, h-waves): fz = h2@W3; wave = (rt3, k-span of 64) ----------
            const int rt3 = wv & 1, ks = wv >> 1;   // ks 0..3
            f32x4 c3 = {0.f, 0.f, 0.f, 0.f};
#pragma unroll
            for (int ki = 0; ki < 2; ++ki) {
                const int kk = ks * 64 + ki * 32;
                bf16x8 a = *(const bf16x8*)&h2s[rt3 * 16 + r][kk + goff];
                bf16x8 b = *(const bf16x8*)&w3t[r][kk + g * 8];
                c3 = __builtin_amdgcn_mfma_f32_16x16x32_bf16(a, b, c3, 0, 0, 0);
            }
#pragma unroll
            for (int q = 0; q < 4; ++q) fzp[ks][rt3 * 16 + g * 4 + q][r] = c3[q];
        } else {
            // ---------- v-waves: div partial = sum_n d2 .* v  (cc holds v = d1@M) ----------
            float p[2][4];
#pragma unroll
            for (int rt = 0; rt < 2; ++rt)
#pragma unroll
                for (int q = 0; q < 4; ++q) p[rt][q] = 0.0f;
#pragma unroll
            for (int ct = 0; ct < 2; ++ct) {
                const int nr = (n0w + ct * 16 + r) ^ wx;   // reader rows g*4+q -> same XOR as writer
#pragma unroll
                for (int rt = 0; rt < 2; ++rt)
#pragma unroll
                    for (int q = 0; q < 4; ++q) {
                        const float d2v = bf2f(d2s[rt * 16 + g * 4 + q][nr]);
                        p[rt][q] = fmaf(d2v, cc[rt][ct][q], p[rt][q]);
                    }
            }
#pragma unroll
            for (int m = 1; m < 16; m <<= 1)
#pragma unroll
                for (int rt = 0; rt < 2; ++rt)
#pragma unroll
                    for (int q = 0; q < 4; ++q) p[rt][q] += __shfl_xor(p[rt][q], m, 64);
            if (r == 0)
#pragma unroll
                for (int rt = 0; rt < 2; ++rt)
#pragma unroll
                    for (int q = 0; q < 4; ++q) divp[wv - 8][rt * 16 + g * 4 + q] = p[rt][q];
        }
        __syncthreads();   // B5: fzp, divp ready

        // ---------- RK4 stage update (fp32, registers; tid<512) ----------
        if (tid < 512) {
            float fz = b3r;
#pragma unroll
            for (int ks = 0; ks < 4; ++ks) fz += fzp[ks][row_u][col_u];
            zacc = fmaf(wst, fz, zacc);
            float znext;
            if (s < 3) {
                const float coef = (s == 2) ? dt : 0.5f * dt;
                znext = fmaf(coef, fz, zbase);
            } else {
                zbase = fmaf(dt6, zacc, zbase);
                znext = zbase;
                zacc = 0.0f;
            }
            zb[row_u][col_u] = f2bf(znext);
            if (col_u == 0) {
                float dv = 0.0f;
#pragma unroll
                for (int w = 0; w < 8; ++w) dv += divp[w][row_u];
                lacc = fmaf(-wst, dv, lacc);
                if (s == 3) { logp = fmaf(dt6, lacc, logp); lacc = 0.0f; }
            }
        }
    }

    // ---------- epilogue: logpz - logp1 ----------
    __syncthreads();
    if (tid < 512) {
        float ss = zbase * zbase;
#pragma unroll
        for (int m = 1; m < 16; m <<= 1) ss += __shfl_xor(ss, m, 64);
        if (col_u == 0)
            out[b0 + row_u] = -0.5f * (ss + (float)DIM * 1.8378770664093453f) - logp;
    }
}

extern "C" void kernel_launch(void* const* d_in, const int* in_sizes, int n_in,
                              void* d_out, int out_size, void* d_ws, size_t ws_size,
                              hipStream_t stream) {
    (void)in_sizes; (void)n_in; (void)out_size; (void)ws_size;
    const float* x  = (const float*)d_in[0];
    const float* W1 = (const float*)d_in[1];
    const float* b1 = (const float*)d_in[2];
    const float* W2 = (const float*)d_in[3];
    const float* b2 = (const float*)d_in[4];
    const float* W3 = (const float*)d_in[5];
    const float* b3 = (const float*)d_in[6];
    unsigned short* w2t = (unsigned short*)d_ws;               // 128 KB
    unsigned short* mt  = w2t + HID * HID;                     // 128 KB

    cnf_setup<<<HID, HID, 0, stream>>>(W1, W2, W3, w2t, mt);
    cnf_main<<<8192 / TILE_B, NTHR, 0, stream>>>(x, W1, b1, b2, b3, w2t, mt, W3, (float*)d_out);
}